// Round 1
// baseline (1696.114 us; speedup 1.0000x reference)
//
#include <hip/hip_runtime.h>

#define N_NODES 50000
#define N_EDGES 800000
#define C 128
#define BN_EPS 1e-5f

// ---- degree count: deg[col[e]] += 1 ----
__global__ void k_deg(const int* __restrict__ col, float* __restrict__ deg) {
    int e = blockIdx.x * blockDim.x + threadIdx.x;
    if (e < N_EDGES) atomicAdd(&deg[col[e]], 1.0f);
}

// ---- dinv = rsqrt(deg + 1)  (self-loop included) ----
__global__ void k_dinv(float* __restrict__ deg) {
    int i = blockIdx.x * blockDim.x + threadIdx.x;
    if (i < N_NODES) deg[i] = rsqrtf(deg[i] + 1.0f);
}

// ---- h = x @ W   (fp32 vector ALU; W staged in LDS) ----
// block (32,8): tx = channel-quad, ty = row-in-block; 8 rows/block
__global__ void __launch_bounds__(256) k_gemm(const float* __restrict__ x,
                                              const float* __restrict__ W,
                                              float* __restrict__ h) {
    __shared__ float4 Ws[C * 32];  // 64 KB, W row-major as float4 quads
    int tid = threadIdx.y * 32 + threadIdx.x;
    const float4* W4 = (const float4*)W;
    for (int i = tid; i < C * 32; i += 256) Ws[i] = W4[i];
    __syncthreads();
    int row = blockIdx.x * 8 + threadIdx.y;
    if (row >= N_NODES) return;
    const float* xr = x + row * C;
    float4 acc = make_float4(0.f, 0.f, 0.f, 0.f);
#pragma unroll 8
    for (int k = 0; k < C; ++k) {
        float xv = xr[k];
        float4 w = Ws[k * 32 + threadIdx.x];
        acc.x += xv * w.x; acc.y += xv * w.y;
        acc.z += xv * w.z; acc.w += xv * w.w;
    }
    ((float4*)h)[row * 32 + threadIdx.x] = acc;
}

// ---- scatter: agg[col] += h[row] * norm ; items >= N_EDGES are self-loops ----
// block (32,8): tx = channel-quad, ty = edge-in-block
__global__ void __launch_bounds__(256) k_scatter(const int* __restrict__ row,
                                                 const int* __restrict__ col,
                                                 const float* __restrict__ dinv,
                                                 const float* __restrict__ h,
                                                 float* __restrict__ agg) {
    int e = blockIdx.x * 8 + threadIdx.y;
    if (e >= N_EDGES + N_NODES) return;
    int s, t; float norm;
    if (e < N_EDGES) {
        s = row[e]; t = col[e];
        norm = dinv[s] * dinv[t];
    } else {
        s = t = e - N_EDGES;
        float d = dinv[s];
        norm = d * d;
    }
    float4 hv = ((const float4*)h)[s * 32 + threadIdx.x];
    float* out = agg + t * C + threadIdx.x * 4;
    atomicAdd(out + 0, hv.x * norm);
    atomicAdd(out + 1, hv.y * norm);
    atomicAdd(out + 2, hv.z * norm);
    atomicAdd(out + 3, hv.w * norm);
}

// ---- per-channel sum / sumsq over nodes ----
// block (128,2); grid-stride over rows
__global__ void __launch_bounds__(256) k_stats(const float* __restrict__ agg,
                                               float* __restrict__ sums,
                                               float* __restrict__ sumsq) {
    int c = threadIdx.x;
    int r0 = blockIdx.x * blockDim.y + threadIdx.y;
    int stride = gridDim.x * blockDim.y;
    float s = 0.f, q = 0.f;
    for (int r = r0; r < N_NODES; r += stride) {
        float v = agg[r * C + c];
        s += v; q += v * v;
    }
    __shared__ float ls[2][C], lq[2][C];
    ls[threadIdx.y][c] = s; lq[threadIdx.y][c] = q;
    __syncthreads();
    if (threadIdx.y == 0) {
        atomicAdd(&sums[c], ls[0][c] + ls[1][c]);
        atomicAdd(&sumsq[c], lq[0][c] + lq[1][c]);
    }
}

// ---- BN params: scale = gamma*rsqrt(var+eps), shift = beta - mean*scale ----
// (bias cancels: (agg+b) - mean(agg+b) == agg - mean(agg))
__global__ void k_bnparams(const float* __restrict__ sums,
                           const float* __restrict__ sumsq,
                           const float* __restrict__ gamma,
                           const float* __restrict__ beta,
                           float* __restrict__ scale,
                           float* __restrict__ shift) {
    int c = threadIdx.x;
    float mean = sums[c] * (1.0f / N_NODES);
    float var = sumsq[c] * (1.0f / N_NODES) - mean * mean;
    float sc = gamma[c] * rsqrtf(var + BN_EPS);
    scale[c] = sc;
    shift[c] = beta[c] - mean * sc;
}

// ---- y = relu(agg*scale + shift), in place on d_out ----
__global__ void __launch_bounds__(256) k_final(float* __restrict__ agg,
                                               const float* __restrict__ scale,
                                               const float* __restrict__ shift) {
    int i = blockIdx.x * blockDim.x + threadIdx.x;  // float4 index
    if (i >= N_NODES * 32) return;
    int cq = i & 31;
    float4 v = ((float4*)agg)[i];
    float4 sc = ((const float4*)scale)[cq];
    float4 sh = ((const float4*)shift)[cq];
    v.x = fmaxf(v.x * sc.x + sh.x, 0.f);
    v.y = fmaxf(v.y * sc.y + sh.y, 0.f);
    v.z = fmaxf(v.z * sc.z + sh.z, 0.f);
    v.w = fmaxf(v.w * sc.w + sh.w, 0.f);
    ((float4*)agg)[i] = v;
}

extern "C" void kernel_launch(void* const* d_in, const int* in_sizes, int n_in,
                              void* d_out, int out_size, void* d_ws, size_t ws_size,
                              hipStream_t stream) {
    const float* x     = (const float*)d_in[0];
    const float* W     = (const float*)d_in[1];
    // d_in[2] = bias: cancels in BatchNorm, unused
    const float* gamma = (const float*)d_in[3];
    const float* beta  = (const float*)d_in[4];
    const int*   eidx  = (const int*)d_in[5];
    const int* row = eidx;
    const int* col = eidx + N_EDGES;

    float* agg = (float*)d_out;           // [N, C] accumulator, finalized in place
    float* h     = (float*)d_ws;          // [N, C]
    float* deg   = h + (size_t)N_NODES * C;  // [N] -> becomes dinv
    float* sums  = deg + N_NODES;         // [C]
    float* sumsq = sums + C;              // [C]
    float* scale = sumsq + C;             // [C]
    float* shift = scale + C;             // [C]

    // zero agg, deg, sums, sumsq (deg/sums/sumsq are contiguous)
    hipMemsetAsync(agg, 0, (size_t)N_NODES * C * sizeof(float), stream);
    hipMemsetAsync(deg, 0, (N_NODES + 2 * C) * sizeof(float), stream);

    k_deg<<<(N_EDGES + 255) / 256, 256, 0, stream>>>(col, deg);
    k_gemm<<<(N_NODES + 7) / 8, dim3(32, 8), 0, stream>>>(x, W, h);
    k_dinv<<<(N_NODES + 255) / 256, 256, 0, stream>>>(deg);
    k_scatter<<<(N_EDGES + N_NODES + 7) / 8, dim3(32, 8), 0, stream>>>(row, col, deg, h, agg);
    k_stats<<<128, dim3(128, 2), 0, stream>>>(agg, sums, sumsq);
    k_bnparams<<<1, 128, 0, stream>>>(sums, sumsq, gamma, beta, scale, shift);
    k_final<<<(N_NODES * 32 + 255) / 256, 256, 0, stream>>>(agg, scale, shift);
}

// Round 2
// 452.170 us; speedup vs baseline: 3.7511x; 3.7511x over previous
//
#include <hip/hip_runtime.h>

#define N_NODES 50000
#define N_EDGES 800000
#define C 128
#define BN_EPS 1e-5f

// ---- degree count: cnt[col[e]] += 1 (int atomics) ----
__global__ void k_count(const int* __restrict__ col, int* __restrict__ cnt) {
    int e = blockIdx.x * blockDim.x + threadIdx.x;
    if (e < N_EDGES) atomicAdd(&cnt[col[e]], 1);
}

// ---- dinv = rsqrt(cnt + 1)  (self-loop included) ----
__global__ void k_dinv(const int* __restrict__ cnt, float* __restrict__ dinv) {
    int i = blockIdx.x * blockDim.x + threadIdx.x;
    if (i < N_NODES) dinv[i] = rsqrtf((float)cnt[i] + 1.0f);
}

// ---- g = dinv[row] * (x @ W)   (fp32 vector ALU; W staged in LDS) ----
// block (32,8): tx = channel-quad, ty = row-in-block; 8 rows/block
__global__ void __launch_bounds__(256) k_gemm(const float* __restrict__ x,
                                              const float* __restrict__ W,
                                              const float* __restrict__ dinv,
                                              float* __restrict__ g) {
    __shared__ float4 Ws[C * 32];  // 64 KB
    int tid = threadIdx.y * 32 + threadIdx.x;
    const float4* W4 = (const float4*)W;
    for (int i = tid; i < C * 32; i += 256) Ws[i] = W4[i];
    __syncthreads();
    int row = blockIdx.x * 8 + threadIdx.y;
    if (row >= N_NODES) return;
    const float* xr = x + row * C;
    float4 acc = make_float4(0.f, 0.f, 0.f, 0.f);
#pragma unroll 8
    for (int k = 0; k < C; ++k) {
        float xv = xr[k];
        float4 w = Ws[k * 32 + threadIdx.x];
        acc.x += xv * w.x; acc.y += xv * w.y;
        acc.z += xv * w.z; acc.w += xv * w.w;
    }
    float d = dinv[row];
    acc.x *= d; acc.y *= d; acc.z *= d; acc.w *= d;
    ((float4*)g)[row * 32 + threadIdx.x] = acc;
}

// ---- exclusive prefix sum over cnt -> offs[N_NODES+1], single block ----
__global__ void __launch_bounds__(1024) k_scan(const int* __restrict__ cnt,
                                               int* __restrict__ offs) {
    __shared__ int wsum[16];
    __shared__ int carry_s;
    int lane = threadIdx.x & 63, wid = threadIdx.x >> 6;
    if (threadIdx.x == 0) carry_s = 0;
    __syncthreads();
    for (int base = 0; base < N_NODES; base += 1024) {
        int i = base + threadIdx.x;
        int v = (i < N_NODES) ? cnt[i] : 0;
        // wave-inclusive scan via shfl
        int sc = v;
#pragma unroll
        for (int d = 1; d < 64; d <<= 1) {
            int t = __shfl_up(sc, d, 64);
            if (lane >= d) sc += t;
        }
        if (lane == 63) wsum[wid] = sc;
        __syncthreads();
        int wadd = carry_s;
        for (int w = 0; w < wid; ++w) wadd += wsum[w];
        if (i < N_NODES) offs[i] = wadd + sc - v;  // exclusive
        __syncthreads();
        if (threadIdx.x == 1023) carry_s = wadd + sc;  // new carry = old + tile total
        __syncthreads();
    }
    if (threadIdx.x == 0) offs[N_NODES] = carry_s;
}

// ---- bucket edges by destination: srcs[offs[t]+cursor[t]++] = row[e] ----
__global__ void k_sort(const int* __restrict__ row, const int* __restrict__ col,
                       const int* __restrict__ offs, int* __restrict__ cursor,
                       int* __restrict__ srcs) {
    int e = blockIdx.x * blockDim.x + threadIdx.x;
    if (e < N_EDGES) {
        int t = col[e];
        int p = offs[t] + atomicAdd(&cursor[t], 1);
        srcs[p] = row[e];
    }
}

// ---- gather: one wave per node; agg[t] = dinv[t]*(sum g[s] + g[t]) ----
__global__ void __launch_bounds__(256) k_gather(const int* __restrict__ offs,
                                                const int* __restrict__ srcs,
                                                const float* __restrict__ g,
                                                const float* __restrict__ dinv,
                                                float* __restrict__ agg) {
    int node = blockIdx.x * 4 + (threadIdx.x >> 6);
    if (node >= N_NODES) return;
    int lane = threadIdx.x & 63;
    int beg = offs[node], end = offs[node + 1];
    const float2* g2 = (const float2*)g;
    float2 acc = g2[(size_t)node * 64 + lane];  // self-loop contribution g[t]
    for (int i = beg; i < end; ++i) {
        int s = srcs[i];
        float2 v = g2[(size_t)s * 64 + lane];
        acc.x += v.x; acc.y += v.y;
    }
    float dt = dinv[node];
    acc.x *= dt; acc.y *= dt;
    ((float2*)agg)[(size_t)node * 64 + lane] = acc;
}

// ---- per-channel sum / sumsq over nodes ----
__global__ void __launch_bounds__(256) k_stats(const float* __restrict__ agg,
                                               float* __restrict__ sums,
                                               float* __restrict__ sumsq) {
    int c = threadIdx.x;
    int r0 = blockIdx.x * blockDim.y + threadIdx.y;
    int stride = gridDim.x * blockDim.y;
    float s = 0.f, q = 0.f;
    for (int r = r0; r < N_NODES; r += stride) {
        float v = agg[r * C + c];
        s += v; q += v * v;
    }
    __shared__ float ls[2][C], lq[2][C];
    ls[threadIdx.y][c] = s; lq[threadIdx.y][c] = q;
    __syncthreads();
    if (threadIdx.y == 0) {
        atomicAdd(&sums[c], ls[0][c] + ls[1][c]);
        atomicAdd(&sumsq[c], lq[0][c] + lq[1][c]);
    }
}

// ---- BN params (bias cancels in BN) ----
__global__ void k_bnparams(const float* __restrict__ sums,
                           const float* __restrict__ sumsq,
                           const float* __restrict__ gamma,
                           const float* __restrict__ beta,
                           float* __restrict__ scale,
                           float* __restrict__ shift) {
    int c = threadIdx.x;
    float mean = sums[c] * (1.0f / N_NODES);
    float var = sumsq[c] * (1.0f / N_NODES) - mean * mean;
    float sc = gamma[c] * rsqrtf(var + BN_EPS);
    scale[c] = sc;
    shift[c] = beta[c] - mean * sc;
}

// ---- y = relu(agg*scale + shift), in place on d_out ----
__global__ void __launch_bounds__(256) k_final(float* __restrict__ agg,
                                               const float* __restrict__ scale,
                                               const float* __restrict__ shift) {
    int i = blockIdx.x * blockDim.x + threadIdx.x;  // float4 index
    if (i >= N_NODES * 32) return;
    int cq = i & 31;
    float4 v = ((float4*)agg)[i];
    float4 sc = ((const float4*)scale)[cq];
    float4 sh = ((const float4*)shift)[cq];
    v.x = fmaxf(v.x * sc.x + sh.x, 0.f);
    v.y = fmaxf(v.y * sc.y + sh.y, 0.f);
    v.z = fmaxf(v.z * sc.z + sh.z, 0.f);
    v.w = fmaxf(v.w * sc.w + sh.w, 0.f);
    ((float4*)agg)[i] = v;
}

extern "C" void kernel_launch(void* const* d_in, const int* in_sizes, int n_in,
                              void* d_out, int out_size, void* d_ws, size_t ws_size,
                              hipStream_t stream) {
    const float* x     = (const float*)d_in[0];
    const float* W     = (const float*)d_in[1];
    // d_in[2] = bias: cancels in BatchNorm, unused
    const float* gamma = (const float*)d_in[3];
    const float* beta  = (const float*)d_in[4];
    const int*   eidx  = (const int*)d_in[5];
    const int* row = eidx;
    const int* col = eidx + N_EDGES;

    float* agg = (float*)d_out;  // [N, C], finalized in place

    // workspace layout
    float* g      = (float*)d_ws;                       // [N, C]
    float* dinv   = g + (size_t)N_NODES * C;            // [N]
    int*   cnt    = (int*)(dinv + N_NODES);             // [N]
    int*   cursor = cnt + N_NODES;                      // [N]
    int*   offs   = cursor + N_NODES;                   // [N+1]
    int*   srcs   = offs + N_NODES + 1;                 // [E]
    float* sums   = (float*)(srcs + N_EDGES);           // [C]
    float* sumsq  = sums + C;                           // [C]
    float* scale  = sumsq + C;                          // [C]
    float* shift  = scale + C;                          // [C]

    // zero cnt+cursor (contiguous) and sums+sumsq (contiguous)
    hipMemsetAsync(cnt, 0, 2 * N_NODES * sizeof(int), stream);
    hipMemsetAsync(sums, 0, 2 * C * sizeof(float), stream);

    k_count<<<(N_EDGES + 255) / 256, 256, 0, stream>>>(col, cnt);
    k_dinv<<<(N_NODES + 255) / 256, 256, 0, stream>>>(cnt, dinv);
    k_gemm<<<(N_NODES + 7) / 8, dim3(32, 8), 0, stream>>>(x, W, dinv, g);
    k_scan<<<1, 1024, 0, stream>>>(cnt, offs);
    k_sort<<<(N_EDGES + 255) / 256, 256, 0, stream>>>(row, col, offs, cursor, srcs);
    k_gather<<<(N_NODES + 3) / 4, 256, 0, stream>>>(offs, srcs, g, dinv, agg);
    k_stats<<<128, dim3(128, 2), 0, stream>>>(agg, sums, sumsq);
    k_bnparams<<<1, 128, 0, stream>>>(sums, sumsq, gamma, beta, scale, shift);
    k_final<<<(N_NODES * 32 + 255) / 256, 256, 0, stream>>>(agg, scale, shift);
}

// Round 3
// 312.418 us; speedup vs baseline: 5.4290x; 1.4473x over previous
//
#include <hip/hip_runtime.h>

#define N_NODES 50000
#define N_EDGES 800000
#define C 128
#define BN_EPS 1e-5f
#define SCAN_BLK 49  // ceil(50000/1024)

// ---- degree count: cnt[col[e]] += 1 (int atomics) ----
__global__ void k_count(const int* __restrict__ col, int* __restrict__ cnt) {
    int e = blockIdx.x * blockDim.x + threadIdx.x;
    if (e < N_EDGES) atomicAdd(&cnt[col[e]], 1);
}

// ---- scan phase 1: per-block (1024-elem chunk) totals ----
__global__ void __launch_bounds__(1024) k_scan1(const int* __restrict__ cnt,
                                                int* __restrict__ blkSum) {
    int i = blockIdx.x * 1024 + threadIdx.x;
    int lane = threadIdx.x & 63, wid = threadIdx.x >> 6;
    int v = (i < N_NODES) ? cnt[i] : 0;
#pragma unroll
    for (int d = 32; d > 0; d >>= 1) v += __shfl_down(v, d, 64);
    __shared__ int ws[16];
    if (lane == 0) ws[wid] = v;
    __syncthreads();
    if (threadIdx.x == 0) {
        int s = 0;
        for (int w = 0; w < 16; ++w) s += ws[w];
        blkSum[blockIdx.x] = s;
    }
}

// ---- scan phase 2: exclusive scan of 49 block sums (1 wave) ----
__global__ void k_scan2(const int* __restrict__ blkSum, int* __restrict__ blkOff,
                        int* __restrict__ offs) {
    int t = threadIdx.x;
    int v = (t < SCAN_BLK) ? blkSum[t] : 0;
    int sc = v;
#pragma unroll
    for (int d = 1; d < 64; d <<= 1) {
        int u = __shfl_up(sc, d, 64);
        if (t >= d) sc += u;
    }
    if (t < SCAN_BLK) blkOff[t] = sc - v;
    if (t == 0) offs[N_NODES] = N_EDGES;  // total degree is known
}

// ---- scan phase 3: per-element exclusive offsets ----
__global__ void __launch_bounds__(1024) k_scan3(const int* __restrict__ cnt,
                                                const int* __restrict__ blkOff,
                                                int* __restrict__ offs) {
    int i = blockIdx.x * 1024 + threadIdx.x;
    int lane = threadIdx.x & 63, wid = threadIdx.x >> 6;
    int v = (i < N_NODES) ? cnt[i] : 0;
    int sc = v;
#pragma unroll
    for (int d = 1; d < 64; d <<= 1) {
        int u = __shfl_up(sc, d, 64);
        if (lane >= d) sc += u;
    }
    __shared__ int ws[16];
    if (lane == 63) ws[wid] = sc;
    __syncthreads();
    int wadd = blkOff[blockIdx.x];
    for (int w = 0; w < wid; ++w) wadd += ws[w];
    if (i < N_NODES) offs[i] = wadd + sc - v;
}

// ---- bucket edges by destination (cursor pre-initialized to offs) ----
__global__ void k_sort(const int* __restrict__ row, const int* __restrict__ col,
                       int* __restrict__ cursor, int* __restrict__ srcs) {
    int e = blockIdx.x * blockDim.x + threadIdx.x;
    if (e < N_EDGES) {
        int t = col[e];
        int p = atomicAdd(&cursor[t], 1);
        srcs[p] = row[e];
    }
}

// ---- g = dinv[row] * (x @ W); 4 rows x 4 cols per thread, W in LDS ----
__global__ void __launch_bounds__(256) k_gemm(const float* __restrict__ x,
                                              const float* __restrict__ W,
                                              const int* __restrict__ cnt,
                                              float* __restrict__ g) {
    __shared__ float4 Ws[C * 32];  // 64 KB
    int tx = threadIdx.x, ty = threadIdx.y;
    int tid = ty * 32 + tx;
    const float4* W4 = (const float4*)W;
    for (int i = tid; i < C * 32; i += 256) Ws[i] = W4[i];
    __syncthreads();
    int r0 = blockIdx.x * 32 + ty * 4;  // N_NODES % 4 == 0: 4-row groups all-or-none
    if (r0 >= N_NODES) return;
    const float* x0 = x + (size_t)r0 * C;
    float4 a0 = {0,0,0,0}, a1 = {0,0,0,0}, a2 = {0,0,0,0}, a3 = {0,0,0,0};
#pragma unroll 8
    for (int k = 0; k < C; ++k) {
        float4 w = Ws[k * 32 + tx];
        float v0 = x0[k], v1 = x0[C + k], v2 = x0[2 * C + k], v3 = x0[3 * C + k];
        a0.x += v0 * w.x; a0.y += v0 * w.y; a0.z += v0 * w.z; a0.w += v0 * w.w;
        a1.x += v1 * w.x; a1.y += v1 * w.y; a1.z += v1 * w.z; a1.w += v1 * w.w;
        a2.x += v2 * w.x; a2.y += v2 * w.y; a2.z += v2 * w.z; a2.w += v2 * w.w;
        a3.x += v3 * w.x; a3.y += v3 * w.y; a3.z += v3 * w.z; a3.w += v3 * w.w;
    }
    float4* g4 = (float4*)g;
    float d0 = rsqrtf((float)cnt[r0] + 1.f);
    float d1 = rsqrtf((float)cnt[r0 + 1] + 1.f);
    float d2 = rsqrtf((float)cnt[r0 + 2] + 1.f);
    float d3 = rsqrtf((float)cnt[r0 + 3] + 1.f);
    a0.x *= d0; a0.y *= d0; a0.z *= d0; a0.w *= d0;
    a1.x *= d1; a1.y *= d1; a1.z *= d1; a1.w *= d1;
    a2.x *= d2; a2.y *= d2; a2.z *= d2; a2.w *= d2;
    a3.x *= d3; a3.y *= d3; a3.z *= d3; a3.w *= d3;
    g4[(size_t)r0 * 32 + tx]       = a0;
    g4[(size_t)(r0 + 1) * 32 + tx] = a1;
    g4[(size_t)(r0 + 2) * 32 + tx] = a2;
    g4[(size_t)(r0 + 3) * 32 + tx] = a3;
}

// ---- gather: one wave per node; agg[t] = dinv[t]*(sum g[s] + g[t]) ----
__global__ void __launch_bounds__(256) k_gather(const int* __restrict__ offs,
                                                const int* __restrict__ srcs,
                                                const float* __restrict__ g,
                                                float* __restrict__ agg) {
    int node = blockIdx.x * 4 + (threadIdx.x >> 6);
    if (node >= N_NODES) return;
    int lane = threadIdx.x & 63;
    int beg = offs[node], end = offs[node + 1];
    const float2* g2 = (const float2*)g;
    float2 acc = g2[(size_t)node * 64 + lane];  // self-loop term
    float2 acc1 = {0.f, 0.f};
    for (int base = beg; base < end; base += 64) {
        int m = end - base; if (m > 64) m = 64;
        int sv = (base + lane < end) ? srcs[base + lane] : 0;  // coalesced batch
        int j = 0;
        for (; j + 1 < m; j += 2) {
            int s0 = __shfl(sv, j, 64);
            int s1 = __shfl(sv, j + 1, 64);
            float2 v0 = g2[(size_t)s0 * 64 + lane];
            float2 v1 = g2[(size_t)s1 * 64 + lane];
            acc.x += v0.x; acc.y += v0.y;
            acc1.x += v1.x; acc1.y += v1.y;
        }
        if (j < m) {
            int s0 = __shfl(sv, j, 64);
            float2 v0 = g2[(size_t)s0 * 64 + lane];
            acc.x += v0.x; acc.y += v0.y;
        }
    }
    float dt = rsqrtf((float)(end - beg) + 1.f);
    acc.x = (acc.x + acc1.x) * dt;
    acc.y = (acc.y + acc1.y) * dt;
    ((float2*)agg)[(size_t)node * 64 + lane] = acc;
}

// ---- per-channel sum / sumsq over nodes (float4 per thread) ----
__global__ void __launch_bounds__(256) k_stats(const float* __restrict__ agg,
                                               float* __restrict__ sums,
                                               float* __restrict__ sumsq) {
    int tx = threadIdx.x;  // channel quad
    int r = blockIdx.x * 8 + threadIdx.y;
    int stride = gridDim.x * 8;
    const float4* a4 = (const float4*)agg;
    float4 s = {0,0,0,0}, q = {0,0,0,0};
    for (; r < N_NODES; r += stride) {
        float4 v = a4[(size_t)r * 32 + tx];
        s.x += v.x; s.y += v.y; s.z += v.z; s.w += v.w;
        q.x += v.x * v.x; q.y += v.y * v.y; q.z += v.z * v.z; q.w += v.w * v.w;
    }
    __shared__ float4 ls[8][32], lq[8][32];
    ls[threadIdx.y][tx] = s; lq[threadIdx.y][tx] = q;
    __syncthreads();
    if (threadIdx.y == 0) {
        for (int w = 1; w < 8; ++w) {
            float4 v = ls[w][tx], u = lq[w][tx];
            s.x += v.x; s.y += v.y; s.z += v.z; s.w += v.w;
            q.x += u.x; q.y += u.y; q.z += u.z; q.w += u.w;
        }
        int c = tx * 4;
        atomicAdd(&sums[c + 0], s.x); atomicAdd(&sums[c + 1], s.y);
        atomicAdd(&sums[c + 2], s.z); atomicAdd(&sums[c + 3], s.w);
        atomicAdd(&sumsq[c + 0], q.x); atomicAdd(&sumsq[c + 1], q.y);
        atomicAdd(&sumsq[c + 2], q.z); atomicAdd(&sumsq[c + 3], q.w);
    }
}

// ---- y = relu(agg*scale + shift); BN params computed per-block in LDS ----
// (bias cancels: (agg+b) - mean(agg+b) == agg - mean(agg))
__global__ void __launch_bounds__(256) k_final(float* __restrict__ agg,
                                               const float* __restrict__ sums,
                                               const float* __restrict__ sumsq,
                                               const float* __restrict__ gamma,
                                               const float* __restrict__ beta) {
    __shared__ float sc_s[C], sh_s[C];
    int tid = threadIdx.x;
    if (tid < C) {
        float mean = sums[tid] * (1.0f / N_NODES);
        float var = sumsq[tid] * (1.0f / N_NODES) - mean * mean;
        float sc = gamma[tid] * rsqrtf(var + BN_EPS);
        sc_s[tid] = sc;
        sh_s[tid] = beta[tid] - mean * sc;
    }
    __syncthreads();
    int i = blockIdx.x * 256 + tid;  // float4 index
    if (i >= N_NODES * 32) return;
    int c = (i & 31) * 4;
    float4 v = ((float4*)agg)[i];
    v.x = fmaxf(v.x * sc_s[c + 0] + sh_s[c + 0], 0.f);
    v.y = fmaxf(v.y * sc_s[c + 1] + sh_s[c + 1], 0.f);
    v.z = fmaxf(v.z * sc_s[c + 2] + sh_s[c + 2], 0.f);
    v.w = fmaxf(v.w * sc_s[c + 3] + sh_s[c + 3], 0.f);
    ((float4*)agg)[i] = v;
}

extern "C" void kernel_launch(void* const* d_in, const int* in_sizes, int n_in,
                              void* d_out, int out_size, void* d_ws, size_t ws_size,
                              hipStream_t stream) {
    const float* x     = (const float*)d_in[0];
    const float* W     = (const float*)d_in[1];
    // d_in[2] = bias: cancels in BatchNorm, unused
    const float* gamma = (const float*)d_in[3];
    const float* beta  = (const float*)d_in[4];
    const int*   eidx  = (const int*)d_in[5];
    const int* row = eidx;
    const int* col = eidx + N_EDGES;

    float* agg = (float*)d_out;  // [N, C], finalized in place

    // workspace layout
    float* g      = (float*)d_ws;                  // [N, C]
    int*   cnt    = (int*)(g + (size_t)N_NODES * C);  // [N]
    int*   offs   = cnt + N_NODES;                 // [N+1]
    int*   cursor = offs + N_NODES + 1;            // [N]
    int*   srcs   = cursor + N_NODES;              // [E]
    int*   blkSum = srcs + N_EDGES;                // [64]
    int*   blkOff = blkSum + 64;                   // [64]
    float* sums   = (float*)(blkOff + 64);         // [C]
    float* sumsq  = sums + C;                      // [C]

    hipMemsetAsync(cnt, 0, N_NODES * sizeof(int), stream);
    hipMemsetAsync(sums, 0, 2 * C * sizeof(float), stream);

    k_count<<<(N_EDGES + 255) / 256, 256, 0, stream>>>(col, cnt);
    k_scan1<<<SCAN_BLK, 1024, 0, stream>>>(cnt, blkSum);
    k_scan2<<<1, 64, 0, stream>>>(blkSum, blkOff, offs);
    k_scan3<<<SCAN_BLK, 1024, 0, stream>>>(cnt, blkOff, offs);
    hipMemcpyAsync(cursor, offs, N_NODES * sizeof(int), hipMemcpyDeviceToDevice, stream);
    k_gemm<<<(N_NODES + 31) / 32, dim3(32, 8), 0, stream>>>(x, W, cnt, g);
    k_sort<<<(N_EDGES + 255) / 256, 256, 0, stream>>>(row, col, cursor, srcs);
    k_gather<<<(N_NODES + 3) / 4, 256, 0, stream>>>(offs, srcs, g, agg);
    k_stats<<<128, dim3(32, 8), 0, stream>>>(agg, sums, sumsq);
    k_final<<<(N_NODES * 32 + 255) / 256, 256, 0, stream>>>(agg, sums, sumsq, gamma, beta);
}

// Round 4
// 293.501 us; speedup vs baseline: 5.7789x; 1.0645x over previous
//
#include <hip/hip_runtime.h>

#define N_NODES 50000
#define N_EDGES 800000
#define C 128
#define BN_EPS 1e-5f
#define SCAN_BLK 49  // ceil(50000/1024)

__device__ __forceinline__ unsigned pack_bf16x2(float a, float b) {
    unsigned ua = __float_as_uint(a);
    ua = (ua + 0x7FFFu + ((ua >> 16) & 1u)) >> 16;   // RNE
    unsigned ub = __float_as_uint(b);
    ub = (ub + 0x7FFFu + ((ub >> 16) & 1u)) >> 16;
    return ua | (ub << 16);
}

// ---- degree count: cnt[col[e]] += 1 (int atomics) ----
__global__ void k_count(const int* __restrict__ col, int* __restrict__ cnt) {
    int e = blockIdx.x * blockDim.x + threadIdx.x;
    if (e < N_EDGES) atomicAdd(&cnt[col[e]], 1);
}

// ---- scan phase 1: per-block (1024-elem chunk) totals ----
__global__ void __launch_bounds__(1024) k_scan1(const int* __restrict__ cnt,
                                                int* __restrict__ blkSum) {
    int i = blockIdx.x * 1024 + threadIdx.x;
    int lane = threadIdx.x & 63, wid = threadIdx.x >> 6;
    int v = (i < N_NODES) ? cnt[i] : 0;
#pragma unroll
    for (int d = 32; d > 0; d >>= 1) v += __shfl_down(v, d, 64);
    __shared__ int ws[16];
    if (lane == 0) ws[wid] = v;
    __syncthreads();
    if (threadIdx.x == 0) {
        int s = 0;
        for (int w = 0; w < 16; ++w) s += ws[w];
        blkSum[blockIdx.x] = s;
    }
}

// ---- scan phase 2: exclusive scan of 49 block sums (1 wave) ----
__global__ void k_scan2(const int* __restrict__ blkSum, int* __restrict__ blkOff,
                        int* __restrict__ offs) {
    int t = threadIdx.x;
    int v = (t < SCAN_BLK) ? blkSum[t] : 0;
    int sc = v;
#pragma unroll
    for (int d = 1; d < 64; d <<= 1) {
        int u = __shfl_up(sc, d, 64);
        if (t >= d) sc += u;
    }
    if (t < SCAN_BLK) blkOff[t] = sc - v;
    if (t == 0) offs[N_NODES] = N_EDGES;  // total degree is known
}

// ---- scan phase 3: per-element exclusive offsets (also seeds cursor) ----
__global__ void __launch_bounds__(1024) k_scan3(const int* __restrict__ cnt,
                                                const int* __restrict__ blkOff,
                                                int* __restrict__ offs,
                                                int* __restrict__ cursor) {
    int i = blockIdx.x * 1024 + threadIdx.x;
    int lane = threadIdx.x & 63, wid = threadIdx.x >> 6;
    int v = (i < N_NODES) ? cnt[i] : 0;
    int sc = v;
#pragma unroll
    for (int d = 1; d < 64; d <<= 1) {
        int u = __shfl_up(sc, d, 64);
        if (lane >= d) sc += u;
    }
    __shared__ int ws[16];
    if (lane == 63) ws[wid] = sc;
    __syncthreads();
    int wadd = blkOff[blockIdx.x];
    for (int w = 0; w < wid; ++w) wadd += ws[w];
    if (i < N_NODES) {
        int ex = wadd + sc - v;
        offs[i] = ex;
        cursor[i] = ex;
    }
}

// ---- bucket edges by destination (cursor pre-initialized to offs) ----
__global__ void k_sort(const int* __restrict__ row, const int* __restrict__ col,
                       int* __restrict__ cursor, int* __restrict__ srcs) {
    int e = blockIdx.x * blockDim.x + threadIdx.x;
    if (e < N_EDGES) {
        int t = col[e];
        int p = atomicAdd(&cursor[t], 1);
        srcs[p] = row[e];
    }
}

// ---- g(bf16) = dinv[row] * (x @ W); 4 rows x 4 cols per thread, W in LDS ----
__global__ void __launch_bounds__(256) k_gemm(const float* __restrict__ x,
                                              const float* __restrict__ W,
                                              const int* __restrict__ cnt,
                                              unsigned* __restrict__ g) {
    __shared__ float4 Ws[C * 32];  // 64 KB
    int tx = threadIdx.x, ty = threadIdx.y;
    int tid = ty * 32 + tx;
    const float4* W4 = (const float4*)W;
    for (int i = tid; i < C * 32; i += 256) Ws[i] = W4[i];
    __syncthreads();
    int r0 = blockIdx.x * 32 + ty * 4;  // N_NODES % 4 == 0
    if (r0 >= N_NODES) return;
    const float* x0 = x + (size_t)r0 * C;
    float4 a0 = {0,0,0,0}, a1 = {0,0,0,0}, a2 = {0,0,0,0}, a3 = {0,0,0,0};
#pragma unroll 8
    for (int k = 0; k < C; ++k) {
        float4 w = Ws[k * 32 + tx];
        float v0 = x0[k], v1 = x0[C + k], v2 = x0[2 * C + k], v3 = x0[3 * C + k];
        a0.x += v0 * w.x; a0.y += v0 * w.y; a0.z += v0 * w.z; a0.w += v0 * w.w;
        a1.x += v1 * w.x; a1.y += v1 * w.y; a1.z += v1 * w.z; a1.w += v1 * w.w;
        a2.x += v2 * w.x; a2.y += v2 * w.y; a2.z += v2 * w.z; a2.w += v2 * w.w;
        a3.x += v3 * w.x; a3.y += v3 * w.y; a3.z += v3 * w.z; a3.w += v3 * w.w;
    }
    float d0 = rsqrtf((float)cnt[r0] + 1.f);
    float d1 = rsqrtf((float)cnt[r0 + 1] + 1.f);
    float d2 = rsqrtf((float)cnt[r0 + 2] + 1.f);
    float d3 = rsqrtf((float)cnt[r0 + 3] + 1.f);
    uint2* g2 = (uint2*)g;
    uint2 p0 = { pack_bf16x2(a0.x * d0, a0.y * d0), pack_bf16x2(a0.z * d0, a0.w * d0) };
    uint2 p1 = { pack_bf16x2(a1.x * d1, a1.y * d1), pack_bf16x2(a1.z * d1, a1.w * d1) };
    uint2 p2 = { pack_bf16x2(a2.x * d2, a2.y * d2), pack_bf16x2(a2.z * d2, a2.w * d2) };
    uint2 p3 = { pack_bf16x2(a3.x * d3, a3.y * d3), pack_bf16x2(a3.z * d3, a3.w * d3) };
    g2[(size_t)r0 * 32 + tx]       = p0;
    g2[(size_t)(r0 + 1) * 32 + tx] = p1;
    g2[(size_t)(r0 + 2) * 32 + tx] = p2;
    g2[(size_t)(r0 + 3) * 32 + tx] = p3;
}

// ---- gather: one wave per node; agg[t] = dinv[t]*(sum g[s] + g[t]) ----
// g row = 64 dwords (bf16x2) = 256 B: lane i holds channels 2i, 2i+1
__global__ void __launch_bounds__(256) k_gather(const int* __restrict__ offs,
                                                const int* __restrict__ srcs,
                                                const unsigned* __restrict__ g,
                                                float* __restrict__ agg) {
    int node = blockIdx.x * 4 + (threadIdx.x >> 6);
    if (node >= N_NODES) return;
    int lane = threadIdx.x & 63;
    int beg = offs[node], end = offs[node + 1];
    unsigned us = g[(size_t)node * 64 + lane];  // self-loop term
    float2 acc, acc1 = {0.f, 0.f};
    acc.x = __uint_as_float(us << 16);
    acc.y = __uint_as_float(us & 0xFFFF0000u);
    for (int base = beg; base < end; base += 64) {
        int m = end - base; if (m > 64) m = 64;
        int sv = (base + lane < end) ? srcs[base + lane] : 0;  // coalesced batch
        int j = 0;
        for (; j + 1 < m; j += 2) {
            int s0 = __shfl(sv, j, 64);
            int s1 = __shfl(sv, j + 1, 64);
            unsigned u0 = g[(size_t)s0 * 64 + lane];
            unsigned u1 = g[(size_t)s1 * 64 + lane];
            acc.x  += __uint_as_float(u0 << 16);
            acc.y  += __uint_as_float(u0 & 0xFFFF0000u);
            acc1.x += __uint_as_float(u1 << 16);
            acc1.y += __uint_as_float(u1 & 0xFFFF0000u);
        }
        if (j < m) {
            int s0 = __shfl(sv, j, 64);
            unsigned u0 = g[(size_t)s0 * 64 + lane];
            acc.x += __uint_as_float(u0 << 16);
            acc.y += __uint_as_float(u0 & 0xFFFF0000u);
        }
    }
    float dt = rsqrtf((float)(end - beg) + 1.f);
    acc.x = (acc.x + acc1.x) * dt;
    acc.y = (acc.y + acc1.y) * dt;
    ((float2*)agg)[(size_t)node * 64 + lane] = acc;
}

// ---- per-channel sum / sumsq over nodes (float4 per thread) ----
__global__ void __launch_bounds__(256) k_stats(const float* __restrict__ agg,
                                               float* __restrict__ sums,
                                               float* __restrict__ sumsq) {
    int tx = threadIdx.x;  // channel quad
    int r = blockIdx.x * 8 + threadIdx.y;
    int stride = gridDim.x * 8;
    const float4* a4 = (const float4*)agg;
    float4 s = {0,0,0,0}, q = {0,0,0,0};
    for (; r < N_NODES; r += stride) {
        float4 v = a4[(size_t)r * 32 + tx];
        s.x += v.x; s.y += v.y; s.z += v.z; s.w += v.w;
        q.x += v.x * v.x; q.y += v.y * v.y; q.z += v.z * v.z; q.w += v.w * v.w;
    }
    __shared__ float4 ls[8][32], lq[8][32];
    ls[threadIdx.y][tx] = s; lq[threadIdx.y][tx] = q;
    __syncthreads();
    if (threadIdx.y == 0) {
        for (int w = 1; w < 8; ++w) {
            float4 v = ls[w][tx], u = lq[w][tx];
            s.x += v.x; s.y += v.y; s.z += v.z; s.w += v.w;
            q.x += u.x; q.y += u.y; q.z += u.z; q.w += u.w;
        }
        int c = tx * 4;
        atomicAdd(&sums[c + 0], s.x); atomicAdd(&sums[c + 1], s.y);
        atomicAdd(&sums[c + 2], s.z); atomicAdd(&sums[c + 3], s.w);
        atomicAdd(&sumsq[c + 0], q.x); atomicAdd(&sumsq[c + 1], q.y);
        atomicAdd(&sumsq[c + 2], q.z); atomicAdd(&sumsq[c + 3], q.w);
    }
}

// ---- y = relu(agg*scale + shift); BN params computed per-block in LDS ----
// (bias cancels: (agg+b) - mean(agg+b) == agg - mean(agg))
__global__ void __launch_bounds__(256) k_final(float* __restrict__ agg,
                                               const float* __restrict__ sums,
                                               const float* __restrict__ sumsq,
                                               const float* __restrict__ gamma,
                                               const float* __restrict__ beta) {
    __shared__ float sc_s[C], sh_s[C];
    int tid = threadIdx.x;
    if (tid < C) {
        float mean = sums[tid] * (1.0f / N_NODES);
        float var = sumsq[tid] * (1.0f / N_NODES) - mean * mean;
        float sc = gamma[tid] * rsqrtf(var + BN_EPS);
        sc_s[tid] = sc;
        sh_s[tid] = beta[tid] - mean * sc;
    }
    __syncthreads();
    int i = blockIdx.x * 256 + tid;  // float4 index
    if (i >= N_NODES * 32) return;
    int c = (i & 31) * 4;
    float4 v = ((float4*)agg)[i];
    v.x = fmaxf(v.x * sc_s[c + 0] + sh_s[c + 0], 0.f);
    v.y = fmaxf(v.y * sc_s[c + 1] + sh_s[c + 1], 0.f);
    v.z = fmaxf(v.z * sc_s[c + 2] + sh_s[c + 2], 0.f);
    v.w = fmaxf(v.w * sc_s[c + 3] + sh_s[c + 3], 0.f);
    ((float4*)agg)[i] = v;
}

extern "C" void kernel_launch(void* const* d_in, const int* in_sizes, int n_in,
                              void* d_out, int out_size, void* d_ws, size_t ws_size,
                              hipStream_t stream) {
    const float* x     = (const float*)d_in[0];
    const float* W     = (const float*)d_in[1];
    // d_in[2] = bias: cancels in BatchNorm, unused
    const float* gamma = (const float*)d_in[3];
    const float* beta  = (const float*)d_in[4];
    const int*   eidx  = (const int*)d_in[5];
    const int* row = eidx;
    const int* col = eidx + N_EDGES;

    float* agg = (float*)d_out;  // [N, C], finalized in place

    // workspace layout
    unsigned* g   = (unsigned*)d_ws;               // [N*64] bf16x2
    int*   cnt    = (int*)(g + (size_t)N_NODES * 64); // [N]
    int*   offs   = cnt + N_NODES;                 // [N+1]
    int*   cursor = offs + N_NODES + 1;            // [N]
    int*   srcs   = cursor + N_NODES;              // [E]
    int*   blkSum = srcs + N_EDGES;                // [64]
    int*   blkOff = blkSum + 64;                   // [64]
    float* sums   = (float*)(blkOff + 64);         // [C]
    float* sumsq  = sums + C;                      // [C]

    hipMemsetAsync(cnt, 0, N_NODES * sizeof(int), stream);
    hipMemsetAsync(sums, 0, 2 * C * sizeof(float), stream);

    k_count<<<(N_EDGES + 255) / 256, 256, 0, stream>>>(col, cnt);
    k_scan1<<<SCAN_BLK, 1024, 0, stream>>>(cnt, blkSum);
    k_scan2<<<1, 64, 0, stream>>>(blkSum, blkOff, offs);
    k_scan3<<<SCAN_BLK, 1024, 0, stream>>>(cnt, blkOff, offs, cursor);
    k_gemm<<<(N_NODES + 31) / 32, dim3(32, 8), 0, stream>>>(x, W, cnt, g);
    k_sort<<<(N_EDGES + 255) / 256, 256, 0, stream>>>(row, col, cursor, srcs);
    k_gather<<<(N_NODES + 3) / 4, 256, 0, stream>>>(offs, srcs, g, agg);
    k_stats<<<128, dim3(32, 8), 0, stream>>>(agg, sums, sumsq);
    k_final<<<(N_NODES * 32 + 255) / 256, 256, 0, stream>>>(agg, sums, sumsq, gamma, beta);
}

// Round 5
// 269.986 us; speedup vs baseline: 6.2822x; 1.0871x over previous
//
#include <hip/hip_runtime.h>

#define N_NODES 50000
#define N_EDGES 800000
#define C 128
#define BN_EPS 1e-5f
#define SCAN_BLK 49  // ceil(50000/1024)

typedef __attribute__((ext_vector_type(8))) short bf16x8;
typedef __attribute__((ext_vector_type(4))) float f32x4;

__device__ __forceinline__ unsigned pack_bf16x2(float a, float b) {
    unsigned ua = __float_as_uint(a);
    ua = (ua + 0x7FFFu + ((ua >> 16) & 1u)) >> 16;   // RNE
    unsigned ub = __float_as_uint(b);
    ub = (ub + 0x7FFFu + ((ub >> 16) & 1u)) >> 16;
    return ua | (ub << 16);
}

__device__ __forceinline__ unsigned short bf16_1(float a) {
    unsigned u = __float_as_uint(a);
    return (unsigned short)((u + 0x7FFFu + ((u >> 16) & 1u)) >> 16);
}

// ---- degree count (int atomics); block 0 also builds WTg = bf16(W^T) ----
__global__ void k_count(const int* __restrict__ col, int* __restrict__ cnt,
                        const float* __restrict__ W, unsigned* __restrict__ WTg) {
    int e = blockIdx.x * blockDim.x + threadIdx.x;
    if (e < N_EDGES) atomicAdd(&cnt[col[e]], 1);
    if (blockIdx.x == 0) {
        // WTg dword j of row n holds bf16(W[2j][n]) | bf16(W[2j+1][n])<<16
#pragma unroll
        for (int it = 0; it < 32; ++it) {
            int i = threadIdx.x + (it << 8);  // 0..8191
            int kh = i & 63;                  // k/2
            int n = i >> 6;                   // 0..127
            float a = W[(kh * 2) * C + n];
            float b = W[(kh * 2 + 1) * C + n];
            WTg[n * 64 + kh] = pack_bf16x2(a, b);
        }
    }
}

// ---- scan phase 1: per-block (1024-elem chunk) totals ----
__global__ void __launch_bounds__(1024) k_scan1(const int* __restrict__ cnt,
                                                int* __restrict__ blkSum) {
    int i = blockIdx.x * 1024 + threadIdx.x;
    int lane = threadIdx.x & 63, wid = threadIdx.x >> 6;
    int v = (i < N_NODES) ? cnt[i] : 0;
#pragma unroll
    for (int d = 32; d > 0; d >>= 1) v += __shfl_down(v, d, 64);
    __shared__ int ws[16];
    if (lane == 0) ws[wid] = v;
    __syncthreads();
    if (threadIdx.x == 0) {
        int s = 0;
        for (int w = 0; w < 16; ++w) s += ws[w];
        blkSum[blockIdx.x] = s;
    }
}

// ---- scan phase 2+3 fused: per-element exclusive offsets (seeds cursor) ----
__global__ void __launch_bounds__(1024) k_scan3(const int* __restrict__ cnt,
                                                const int* __restrict__ blkSum,
                                                int* __restrict__ offs,
                                                int* __restrict__ cursor) {
    __shared__ int base_s;
    __shared__ int ws[16];
    if (threadIdx.x == 0) {
        int b = 0;
        for (int w = 0; w < (int)blockIdx.x; ++w) b += blkSum[w];
        base_s = b;
        if (blockIdx.x == 0) offs[N_NODES] = N_EDGES;  // total degree known
    }
    int i = blockIdx.x * 1024 + threadIdx.x;
    int lane = threadIdx.x & 63, wid = threadIdx.x >> 6;
    int v = (i < N_NODES) ? cnt[i] : 0;
    int sc = v;
#pragma unroll
    for (int d = 1; d < 64; d <<= 1) {
        int u = __shfl_up(sc, d, 64);
        if (lane >= d) sc += u;
    }
    if (lane == 63) ws[wid] = sc;
    __syncthreads();
    int wadd = base_s;
    for (int w = 0; w < wid; ++w) wadd += ws[w];
    if (i < N_NODES) {
        int ex = wadd + sc - v;
        offs[i] = ex;
        cursor[i] = ex;
    }
}

// ---- bucket edges by destination (cursor pre-initialized to offs) ----
__global__ void k_sort(const int* __restrict__ row, const int* __restrict__ col,
                       int* __restrict__ cursor, int* __restrict__ srcs) {
    int e = blockIdx.x * blockDim.x + threadIdx.x;
    if (e < N_EDGES) {
        int t = col[e];
        int p = atomicAdd(&cursor[t], 1);
        srcs[p] = row[e];
    }
}

// ---- g(bf16) = dinv[row]*(x@W) via MFMA 16x16x32 bf16 ----
// block = 256 thr = 4 waves; 64 rows/block (16/wave); x-tile staged bf16 in LDS;
// B-fragments read from global WTg (32 KB, L2-resident).
__global__ void __launch_bounds__(256) k_gemm(const float* __restrict__ x,
                                              const unsigned* __restrict__ WTg,
                                              const int* __restrict__ cnt,
                                              unsigned short* __restrict__ g) {
    __shared__ unsigned xs[64 * 68];  // 64 rows x 68 dwords (136 bf16: 128 + 8 pad)
    int tid = threadIdx.x;
    int r0 = blockIdx.x * 64;
    const float4* x4 = (const float4*)x;
#pragma unroll
    for (int it = 0; it < 8; ++it) {
        int i = tid + (it << 8);        // float4 unit within 64x128 tile
        int row = i >> 5, c4 = i & 31;
        float4 v = {0.f, 0.f, 0.f, 0.f};
        if (r0 + row < N_NODES) v = x4[(size_t)(r0 + row) * 32 + c4];
        xs[row * 68 + c4 * 2]     = pack_bf16x2(v.x, v.y);
        xs[row * 68 + c4 * 2 + 1] = pack_bf16x2(v.z, v.w);
    }
    __syncthreads();
    int wave = tid >> 6, lane = tid & 63;
    int r0w = r0 + wave * 16;
    if (r0w >= N_NODES) return;
    int m = lane & 15, q = lane >> 4;
    bf16x8 afrag[4];
#pragma unroll
    for (int kt = 0; kt < 4; ++kt)
        afrag[kt] = *(const bf16x8*)&xs[(wave * 16 + m) * 68 + kt * 16 + q * 4];
    const uint4* B4 = (const uint4*)WTg;
    int bbase = m * 16 + q;
    f32x4 acc[8];
#pragma unroll
    for (int nt = 0; nt < 8; ++nt)
        acc[nt][0] = acc[nt][1] = acc[nt][2] = acc[nt][3] = 0.f;
#pragma unroll
    for (int nt = 0; nt < 8; ++nt) {
#pragma unroll
        for (int kt = 0; kt < 4; ++kt) {
            uint4 braw = B4[nt * 256 + kt * 4 + bbase];
            bf16x8 bfrag = __builtin_bit_cast(bf16x8, braw);
            acc[nt] = __builtin_amdgcn_mfma_f32_16x16x32_bf16(afrag[kt], bfrag, acc[nt], 0, 0, 0);
        }
    }
    // epilogue: scale rows by dinv, pack bf16.  D: col=lane&15, row=q*4+reg
    int rb = r0w + q * 4;
    float dv[4];
#pragma unroll
    for (int reg = 0; reg < 4; ++reg) dv[reg] = rsqrtf((float)cnt[rb + reg] + 1.f);
#pragma unroll
    for (int nt = 0; nt < 8; ++nt) {
        int cbase = nt * 16 + m;
#pragma unroll
        for (int reg = 0; reg < 4; ++reg)
            g[(size_t)(rb + reg) * C + cbase] = bf16_1(acc[nt][reg] * dv[reg]);
    }
}

// ---- gather: one wave per node; agg[t] = dinv[t]*(sum g[s] + g[t]) ----
// g row = 64 dwords (bf16x2) = 256 B: lane i holds channels 2i, 2i+1
__global__ void __launch_bounds__(256) k_gather(const int* __restrict__ offs,
                                                const int* __restrict__ srcs,
                                                const unsigned* __restrict__ g,
                                                float* __restrict__ agg) {
    int node = blockIdx.x * 4 + (threadIdx.x >> 6);
    if (node >= N_NODES) return;
    int lane = threadIdx.x & 63;
    int beg = offs[node], end = offs[node + 1];
    unsigned us = g[(size_t)node * 64 + lane];  // self-loop term
    float2 acc, acc1 = {0.f, 0.f};
    acc.x = __uint_as_float(us << 16);
    acc.y = __uint_as_float(us & 0xFFFF0000u);
    for (int base = beg; base < end; base += 64) {
        int m = end - base; if (m > 64) m = 64;
        int sv = (base + lane < end) ? srcs[base + lane] : 0;  // coalesced batch
        int j = 0;
        for (; j + 1 < m; j += 2) {
            int s0 = __shfl(sv, j, 64);
            int s1 = __shfl(sv, j + 1, 64);
            unsigned u0 = g[(size_t)s0 * 64 + lane];
            unsigned u1 = g[(size_t)s1 * 64 + lane];
            acc.x  += __uint_as_float(u0 << 16);
            acc.y  += __uint_as_float(u0 & 0xFFFF0000u);
            acc1.x += __uint_as_float(u1 << 16);
            acc1.y += __uint_as_float(u1 & 0xFFFF0000u);
        }
        if (j < m) {
            int s0 = __shfl(sv, j, 64);
            unsigned u0 = g[(size_t)s0 * 64 + lane];
            acc.x += __uint_as_float(u0 << 16);
            acc.y += __uint_as_float(u0 & 0xFFFF0000u);
        }
    }
    float dt = rsqrtf((float)(end - beg) + 1.f);
    acc.x = (acc.x + acc1.x) * dt;
    acc.y = (acc.y + acc1.y) * dt;
    ((float2*)agg)[(size_t)node * 64 + lane] = acc;
}

// ---- per-channel sum / sumsq over nodes (float4 per thread) ----
__global__ void __launch_bounds__(256) k_stats(const float* __restrict__ agg,
                                               float* __restrict__ sums,
                                               float* __restrict__ sumsq) {
    int tx = threadIdx.x;  // channel quad
    int r = blockIdx.x * 8 + threadIdx.y;
    int stride = gridDim.x * 8;
    const float4* a4 = (const float4*)agg;
    float4 s = {0,0,0,0}, q = {0,0,0,0};
    for (; r < N_NODES; r += stride) {
        float4 v = a4[(size_t)r * 32 + tx];
        s.x += v.x; s.y += v.y; s.z += v.z; s.w += v.w;
        q.x += v.x * v.x; q.y += v.y * v.y; q.z += v.z * v.z; q.w += v.w * v.w;
    }
    __shared__ float4 ls[8][32], lq[8][32];
    ls[threadIdx.y][tx] = s; lq[threadIdx.y][tx] = q;
    __syncthreads();
    if (threadIdx.y == 0) {
        for (int w = 1; w < 8; ++w) {
            float4 v = ls[w][tx], u = lq[w][tx];
            s.x += v.x; s.y += v.y; s.z += v.z; s.w += v.w;
            q.x += u.x; q.y += u.y; q.z += u.z; q.w += u.w;
        }
        int c = tx * 4;
        atomicAdd(&sums[c + 0], s.x); atomicAdd(&sums[c + 1], s.y);
        atomicAdd(&sums[c + 2], s.z); atomicAdd(&sums[c + 3], s.w);
        atomicAdd(&sumsq[c + 0], q.x); atomicAdd(&sumsq[c + 1], q.y);
        atomicAdd(&sumsq[c + 2], q.z); atomicAdd(&sumsq[c + 3], q.w);
    }
}

// ---- y = relu(agg*scale + shift); BN params computed per-block in LDS ----
// (bias cancels: (agg+b) - mean(agg+b) == agg - mean(agg))
__global__ void __launch_bounds__(256) k_final(float* __restrict__ agg,
                                               const float* __restrict__ sums,
                                               const float* __restrict__ sumsq,
                                               const float* __restrict__ gamma,
                                               const float* __restrict__ beta) {
    __shared__ float sc_s[C], sh_s[C];
    int tid = threadIdx.x;
    if (tid < C) {
        float mean = sums[tid] * (1.0f / N_NODES);
        float var = sumsq[tid] * (1.0f / N_NODES) - mean * mean;
        float sc = gamma[tid] * rsqrtf(var + BN_EPS);
        sc_s[tid] = sc;
        sh_s[tid] = beta[tid] - mean * sc;
    }
    __syncthreads();
    int i = blockIdx.x * 256 + tid;  // float4 index
    if (i >= N_NODES * 32) return;
    int c = (i & 31) * 4;
    float4 v = ((float4*)agg)[i];
    v.x = fmaxf(v.x * sc_s[c + 0] + sh_s[c + 0], 0.f);
    v.y = fmaxf(v.y * sc_s[c + 1] + sh_s[c + 1], 0.f);
    v.z = fmaxf(v.z * sc_s[c + 2] + sh_s[c + 2], 0.f);
    v.w = fmaxf(v.w * sc_s[c + 3] + sh_s[c + 3], 0.f);
    ((float4*)agg)[i] = v;
}

extern "C" void kernel_launch(void* const* d_in, const int* in_sizes, int n_in,
                              void* d_out, int out_size, void* d_ws, size_t ws_size,
                              hipStream_t stream) {
    const float* x     = (const float*)d_in[0];
    const float* W     = (const float*)d_in[1];
    // d_in[2] = bias: cancels in BatchNorm, unused
    const float* gamma = (const float*)d_in[3];
    const float* beta  = (const float*)d_in[4];
    const int*   eidx  = (const int*)d_in[5];
    const int* row = eidx;
    const int* col = eidx + N_EDGES;

    float* agg = (float*)d_out;  // [N, C], finalized in place

    // workspace layout
    unsigned* g   = (unsigned*)d_ws;                  // [N*64] bf16x2
    int*   cnt    = (int*)(g + (size_t)N_NODES * 64); // [N]
    int*   offs   = cnt + N_NODES;                    // [N+1]
    int*   cursor = offs + N_NODES + 1;               // [N]
    int*   srcs   = cursor + N_NODES;                 // [E]
    int*   blkSum = srcs + N_EDGES;                   // [64]
    unsigned* WTg = (unsigned*)(blkSum + 64);         // [128*64] bf16x2 (W^T)
    float* sums   = (float*)(WTg + 128 * 64);         // [C]
    float* sumsq  = sums + C;                         // [C]

    hipMemsetAsync(cnt, 0, N_NODES * sizeof(int), stream);
    hipMemsetAsync(sums, 0, 2 * C * sizeof(float), stream);

    k_count<<<(N_EDGES + 255) / 256, 256, 0, stream>>>(col, cnt, W, WTg);
    k_scan1<<<SCAN_BLK, 1024, 0, stream>>>(cnt, blkSum);
    k_scan3<<<SCAN_BLK, 1024, 0, stream>>>(cnt, blkSum, offs, cursor);
    k_gemm<<<(N_NODES + 63) / 64, 256, 0, stream>>>(x, WTg, cnt, (unsigned short*)g);
    k_sort<<<(N_EDGES + 255) / 256, 256, 0, stream>>>(row, col, cursor, srcs);
    k_gather<<<(N_NODES + 3) / 4, 256, 0, stream>>>(offs, srcs, g, agg);
    k_stats<<<128, dim3(32, 8), 0, stream>>>(agg, sums, sumsq);
    k_final<<<(N_NODES * 32 + 255) / 256, 256, 0, stream>>>(agg, sums, sumsq, gamma, beta);
}

// Round 6
// 237.585 us; speedup vs baseline: 7.1390x; 1.1364x over previous
//
#include <hip/hip_runtime.h>

#define N_NODES 50000
#define N_EDGES 800000
#define C 128
#define BN_EPS 1e-5f
#define BSHIFT 7                              // 128 nodes per bucket
#define NBUCK ((N_NODES + 127) >> BSHIFT)     // 391
#define EPB 8192                              // edges per block (phase A)
#define A_BLOCKS ((N_EDGES + EPB - 1) / EPB)  // 98

typedef __attribute__((ext_vector_type(8))) short bf16x8;
typedef __attribute__((ext_vector_type(4))) float f32x4;

__device__ __forceinline__ unsigned pack_bf16x2(float a, float b) {
    unsigned ua = __float_as_uint(a);
    ua = (ua + 0x7FFFu + ((ua >> 16) & 1u)) >> 16;   // RNE
    unsigned ub = __float_as_uint(b);
    ub = (ub + 0x7FFFu + ((ub >> 16) & 1u)) >> 16;
    return ua | (ub << 16);
}

__device__ __forceinline__ unsigned short bf16_1(float a) {
    unsigned u = __float_as_uint(a);
    return (unsigned short)((u + 0x7FFFu + ((u >> 16) & 1u)) >> 16);
}

// ---- phase A1: coarse bucket histogram; block 0 also builds WTg = bf16(W^T) ----
__global__ void __launch_bounds__(256) k_bhist(const int* __restrict__ col,
                                               int* __restrict__ bCnt,
                                               const float* __restrict__ W,
                                               unsigned* __restrict__ WTg) {
    __shared__ int hist[NBUCK];
    for (int i = threadIdx.x; i < NBUCK; i += 256) hist[i] = 0;
    __syncthreads();
    int e0 = blockIdx.x * EPB;
    int e1 = e0 + EPB; if (e1 > N_EDGES) e1 = N_EDGES;
    for (int e = e0 + threadIdx.x; e < e1; e += 256)
        atomicAdd(&hist[col[e] >> BSHIFT], 1);
    if (blockIdx.x == 0) {
        // WTg dword j of row n holds bf16(W[2j][n]) | bf16(W[2j+1][n])<<16
#pragma unroll
        for (int it = 0; it < 32; ++it) {
            int i = threadIdx.x + (it << 8);
            int kh = i & 63, n = i >> 6;
            WTg[n * 64 + kh] = pack_bf16x2(W[(kh * 2) * C + n], W[(kh * 2 + 1) * C + n]);
        }
    }
    __syncthreads();
    for (int i = threadIdx.x; i < NBUCK; i += 256)
        if (hist[i]) atomicAdd(&bCnt[i], hist[i]);
}

// ---- bucket scan: bStart/bCur = exclusive scan of bCnt ----
__global__ void __launch_bounds__(512) k_bscan(const int* __restrict__ bCnt,
                                               int* __restrict__ bStart,
                                               int* __restrict__ bCur,
                                               int* __restrict__ offs) {
    __shared__ int ws[8];
    int t = threadIdx.x, lane = t & 63, wid = t >> 6;
    int v = (t < NBUCK) ? bCnt[t] : 0;
    int sc = v;
#pragma unroll
    for (int d = 1; d < 64; d <<= 1) {
        int u = __shfl_up(sc, d, 64);
        if (lane >= d) sc += u;
    }
    if (lane == 63) ws[wid] = sc;
    __syncthreads();
    int add = 0;
    for (int w = 0; w < wid; ++w) add += ws[w];
    if (t < NBUCK) { int ex = add + sc - v; bStart[t] = ex; bCur[t] = ex; }
    if (t == 0) { bStart[NBUCK] = N_EDGES; offs[N_NODES] = N_EDGES; }
}

// ---- phase A2: scatter packed edges (src | dst<<16) into coarse buckets ----
__global__ void __launch_bounds__(256) k_bscatter(const int* __restrict__ row,
                                                  const int* __restrict__ col,
                                                  int* __restrict__ bCur,
                                                  unsigned* __restrict__ bEdges) {
    __shared__ int hist[NBUCK];
    __shared__ int lbase[NBUCK];
    for (int i = threadIdx.x; i < NBUCK; i += 256) hist[i] = 0;
    __syncthreads();
    int e0 = blockIdx.x * EPB;
    int e1 = e0 + EPB; if (e1 > N_EDGES) e1 = N_EDGES;
    for (int e = e0 + threadIdx.x; e < e1; e += 256)
        atomicAdd(&hist[col[e] >> BSHIFT], 1);
    __syncthreads();
    for (int i = threadIdx.x; i < NBUCK; i += 256) {
        int h = hist[i];
        lbase[i] = h ? atomicAdd(&bCur[i], h) : 0;
        hist[i] = 0;
    }
    __syncthreads();
    for (int e = e0 + threadIdx.x; e < e1; e += 256) {
        int d = col[e];
        int b = d >> BSHIFT;
        int r = atomicAdd(&hist[b], 1);
        bEdges[lbase[b] + r] = (unsigned)row[e] | ((unsigned)d << 16);
    }
}

// ---- phase B: per-bucket node histogram + scan -> offs/cnt, scatter srcs ----
__global__ void __launch_bounds__(256) k_bsort(const unsigned* __restrict__ bEdges,
                                               const int* __restrict__ bStart,
                                               int* __restrict__ offs,
                                               int* __restrict__ cnt,
                                               unsigned short* __restrict__ srcs) {
    __shared__ int h[128];
    __shared__ int wtot;
    int tid = threadIdx.x;
    int b = blockIdx.x;
    int n0 = b << BSHIFT;
    int nn = N_NODES - n0; if (nn > 128) nn = 128;
    int e0 = bStart[b], e1 = bStart[b + 1];
    if (tid < 128) h[tid] = 0;
    __syncthreads();
    for (int e = e0 + tid; e < e1; e += 256)
        atomicAdd(&h[(int)(bEdges[e] >> 16) - n0], 1);
    __syncthreads();
    int v = 0, sc = 0;
    if (tid < 128) {
        int lane = tid & 63;
        v = h[tid];
        sc = v;
#pragma unroll
        for (int d = 1; d < 64; d <<= 1) {
            int u = __shfl_up(sc, d, 64);
            if (lane >= d) sc += u;
        }
        if (tid == 63) wtot = sc;
    }
    __syncthreads();
    if (tid < 128) {
        int ex = sc - v + ((tid >= 64) ? wtot : 0);
        if (tid < nn) { offs[n0 + tid] = e0 + ex; cnt[n0 + tid] = v; }
        h[tid] = ex;  // reuse as cursor
    }
    __syncthreads();
    for (int e = e0 + tid; e < e1; e += 256) {
        unsigned pe = bEdges[e];
        int r = atomicAdd(&h[(int)(pe >> 16) - n0], 1);
        srcs[e0 + r] = (unsigned short)(pe & 0xFFFFu);
    }
}

// ---- g(bf16) = dinv[row]*(x@W) via MFMA 16x16x32 bf16 ----
__global__ void __launch_bounds__(256) k_gemm(const float* __restrict__ x,
                                              const unsigned* __restrict__ WTg,
                                              const int* __restrict__ cnt,
                                              unsigned short* __restrict__ g) {
    __shared__ unsigned xs[64 * 68];  // 64 rows x 68 dwords (128 bf16 + pad)
    int tid = threadIdx.x;
    int r0 = blockIdx.x * 64;
    const float4* x4 = (const float4*)x;
#pragma unroll
    for (int it = 0; it < 8; ++it) {
        int i = tid + (it << 8);
        int row = i >> 5, c4 = i & 31;
        float4 v = {0.f, 0.f, 0.f, 0.f};
        if (r0 + row < N_NODES) v = x4[(size_t)(r0 + row) * 32 + c4];
        xs[row * 68 + c4 * 2]     = pack_bf16x2(v.x, v.y);
        xs[row * 68 + c4 * 2 + 1] = pack_bf16x2(v.z, v.w);
    }
    __syncthreads();
    int wave = tid >> 6, lane = tid & 63;
    int r0w = r0 + wave * 16;
    if (r0w >= N_NODES) return;
    int m = lane & 15, q = lane >> 4;
    bf16x8 afrag[4];
#pragma unroll
    for (int kt = 0; kt < 4; ++kt)
        afrag[kt] = *(const bf16x8*)&xs[(wave * 16 + m) * 68 + kt * 16 + q * 4];
    const uint4* B4 = (const uint4*)WTg;
    int bbase = m * 16 + q;
    f32x4 acc[8];
#pragma unroll
    for (int nt = 0; nt < 8; ++nt)
        acc[nt][0] = acc[nt][1] = acc[nt][2] = acc[nt][3] = 0.f;
#pragma unroll
    for (int nt = 0; nt < 8; ++nt) {
#pragma unroll
        for (int kt = 0; kt < 4; ++kt) {
            uint4 braw = B4[nt * 256 + kt * 4 + bbase];
            bf16x8 bfrag = __builtin_bit_cast(bf16x8, braw);
            acc[nt] = __builtin_amdgcn_mfma_f32_16x16x32_bf16(afrag[kt], bfrag, acc[nt], 0, 0, 0);
        }
    }
    int rb = r0w + q * 4;
    float dv[4];
#pragma unroll
    for (int reg = 0; reg < 4; ++reg) dv[reg] = rsqrtf((float)cnt[rb + reg] + 1.f);
#pragma unroll
    for (int nt = 0; nt < 8; ++nt) {
        int cbase = nt * 16 + m;
#pragma unroll
        for (int reg = 0; reg < 4; ++reg)
            g[(size_t)(rb + reg) * C + cbase] = bf16_1(acc[nt][reg] * dv[reg]);
    }
}

// ---- gather: one wave per node; agg[t] = dinv[t]*(sum g[s] + g[t]) ----
__global__ void __launch_bounds__(256) k_gather(const int* __restrict__ offs,
                                                const unsigned short* __restrict__ srcs,
                                                const unsigned* __restrict__ g,
                                                float* __restrict__ agg) {
    int node = blockIdx.x * 4 + (threadIdx.x >> 6);
    if (node >= N_NODES) return;
    int lane = threadIdx.x & 63;
    int beg = offs[node], end = offs[node + 1];
    unsigned us = g[(size_t)node * 64 + lane];  // self-loop term
    float2 acc, acc1 = {0.f, 0.f};
    acc.x = __uint_as_float(us << 16);
    acc.y = __uint_as_float(us & 0xFFFF0000u);
    for (int base = beg; base < end; base += 64) {
        int m = end - base; if (m > 64) m = 64;
        int sv = (base + lane < end) ? (int)srcs[base + lane] : 0;
        int j = 0;
        for (; j + 1 < m; j += 2) {
            int s0 = __shfl(sv, j, 64);
            int s1 = __shfl(sv, j + 1, 64);
            unsigned u0 = g[(size_t)s0 * 64 + lane];
            unsigned u1 = g[(size_t)s1 * 64 + lane];
            acc.x  += __uint_as_float(u0 << 16);
            acc.y  += __uint_as_float(u0 & 0xFFFF0000u);
            acc1.x += __uint_as_float(u1 << 16);
            acc1.y += __uint_as_float(u1 & 0xFFFF0000u);
        }
        if (j < m) {
            int s0 = __shfl(sv, j, 64);
            unsigned u0 = g[(size_t)s0 * 64 + lane];
            acc.x += __uint_as_float(u0 << 16);
            acc.y += __uint_as_float(u0 & 0xFFFF0000u);
        }
    }
    float dt = rsqrtf((float)(end - beg) + 1.f);
    acc.x = (acc.x + acc1.x) * dt;
    acc.y = (acc.y + acc1.y) * dt;
    ((float2*)agg)[(size_t)node * 64 + lane] = acc;
}

// ---- per-channel sum / sumsq over nodes ----
__global__ void __launch_bounds__(256) k_stats(const float* __restrict__ agg,
                                               float* __restrict__ sums,
                                               float* __restrict__ sumsq) {
    int tx = threadIdx.x;
    int r = blockIdx.x * 8 + threadIdx.y;
    int stride = gridDim.x * 8;
    const float4* a4 = (const float4*)agg;
    float4 s = {0,0,0,0}, q = {0,0,0,0};
    for (; r < N_NODES; r += stride) {
        float4 v = a4[(size_t)r * 32 + tx];
        s.x += v.x; s.y += v.y; s.z += v.z; s.w += v.w;
        q.x += v.x * v.x; q.y += v.y * v.y; q.z += v.z * v.z; q.w += v.w * v.w;
    }
    __shared__ float4 ls[8][32], lq[8][32];
    ls[threadIdx.y][tx] = s; lq[threadIdx.y][tx] = q;
    __syncthreads();
    if (threadIdx.y == 0) {
        for (int w = 1; w < 8; ++w) {
            float4 v = ls[w][tx], u = lq[w][tx];
            s.x += v.x; s.y += v.y; s.z += v.z; s.w += v.w;
            q.x += u.x; q.y += u.y; q.z += u.z; q.w += u.w;
        }
        int c = tx * 4;
        atomicAdd(&sums[c + 0], s.x); atomicAdd(&sums[c + 1], s.y);
        atomicAdd(&sums[c + 2], s.z); atomicAdd(&sums[c + 3], s.w);
        atomicAdd(&sumsq[c + 0], q.x); atomicAdd(&sumsq[c + 1], q.y);
        atomicAdd(&sumsq[c + 2], q.z); atomicAdd(&sumsq[c + 3], q.w);
    }
}

// ---- y = relu(agg*scale + shift); bias cancels in BN ----
__global__ void __launch_bounds__(256) k_final(float* __restrict__ agg,
                                               const float* __restrict__ sums,
                                               const float* __restrict__ sumsq,
                                               const float* __restrict__ gamma,
                                               const float* __restrict__ beta) {
    __shared__ float sc_s[C], sh_s[C];
    int tid = threadIdx.x;
    if (tid < C) {
        float mean = sums[tid] * (1.0f / N_NODES);
        float var = sumsq[tid] * (1.0f / N_NODES) - mean * mean;
        float sc = gamma[tid] * rsqrtf(var + BN_EPS);
        sc_s[tid] = sc;
        sh_s[tid] = beta[tid] - mean * sc;
    }
    __syncthreads();
    int i = blockIdx.x * 256 + tid;
    if (i >= N_NODES * 32) return;
    int c = (i & 31) * 4;
    float4 v = ((float4*)agg)[i];
    v.x = fmaxf(v.x * sc_s[c + 0] + sh_s[c + 0], 0.f);
    v.y = fmaxf(v.y * sc_s[c + 1] + sh_s[c + 1], 0.f);
    v.z = fmaxf(v.z * sc_s[c + 2] + sh_s[c + 2], 0.f);
    v.w = fmaxf(v.w * sc_s[c + 3] + sh_s[c + 3], 0.f);
    ((float4*)agg)[i] = v;
}

extern "C" void kernel_launch(void* const* d_in, const int* in_sizes, int n_in,
                              void* d_out, int out_size, void* d_ws, size_t ws_size,
                              hipStream_t stream) {
    const float* x     = (const float*)d_in[0];
    const float* W     = (const float*)d_in[1];
    // d_in[2] = bias: cancels in BatchNorm, unused
    const float* gamma = (const float*)d_in[3];
    const float* beta  = (const float*)d_in[4];
    const int*   eidx  = (const int*)d_in[5];
    const int* row = eidx;
    const int* col = eidx + N_EDGES;

    float* agg = (float*)d_out;  // [N, C], finalized in place

    // workspace layout
    unsigned* g      = (unsigned*)d_ws;                  // [N*64] bf16x2
    unsigned* bEdges = g + (size_t)N_NODES * 64;         // [E] packed src|dst<<16
    int*   cnt    = (int*)(bEdges + N_EDGES);            // [N]
    int*   offs   = cnt + N_NODES;                       // [N+1]
    int*   bCnt   = offs + N_NODES + 1;                  // [NBUCK+1]
    int*   bStart = bCnt + NBUCK + 1;                    // [NBUCK+1]
    int*   bCur   = bStart + NBUCK + 1;                  // [NBUCK]
    unsigned* WTg = (unsigned*)(bCur + NBUCK);           // [128*64] bf16x2 (W^T)
    float* sums   = (float*)(WTg + 128 * 64);            // [C]
    float* sumsq  = sums + C;                            // [C]
    unsigned short* srcs = (unsigned short*)(sumsq + C); // [E] u16

    hipMemsetAsync(bCnt, 0, (NBUCK + 1) * sizeof(int), stream);
    hipMemsetAsync(sums, 0, 2 * C * sizeof(float), stream);

    k_bhist<<<A_BLOCKS, 256, 0, stream>>>(col, bCnt, W, WTg);
    k_bscan<<<1, 512, 0, stream>>>(bCnt, bStart, bCur, offs);
    k_bscatter<<<A_BLOCKS, 256, 0, stream>>>(row, col, bCur, bEdges);
    k_bsort<<<NBUCK, 256, 0, stream>>>(bEdges, bStart, offs, cnt, srcs);
    k_gemm<<<(N_NODES + 63) / 64, 256, 0, stream>>>(x, WTg, cnt, (unsigned short*)g);
    k_gather<<<(N_NODES + 3) / 4, 256, 0, stream>>>(offs, srcs, g, agg);
    k_stats<<<128, dim3(32, 8), 0, stream>>>(agg, sums, sumsq);
    k_final<<<(N_NODES * 32 + 255) / 256, 256, 0, stream>>>(agg, sums, sumsq, gamma, beta);
}